// Round 10
// baseline (267.086 us; speedup 1.0000x reference)
//
#include <hip/hip_runtime.h>
#include <hip/hip_bf16.h>

typedef __attribute__((ext_vector_type(8))) short bf16x8;
typedef __attribute__((ext_vector_type(4))) float f32x4;

union U8 { uint4 u; bf16x8 v; };

// ---------- bf16 helpers ----------
__device__ __forceinline__ float bf2f(unsigned short u) {
    return __uint_as_float(((unsigned)u) << 16);
}
__device__ __forceinline__ unsigned short f2bf(float f) {
    unsigned u = __float_as_uint(f);
    u += 0x7fffu + ((u >> 16) & 1u);
    return (unsigned short)(u >> 16);
}
__device__ __forceinline__ unsigned pk2bf(float a, float b) {
    __hip_bfloat162 h = __float22bfloat162_rn(make_float2(a, b));
    union { __hip_bfloat162 h; unsigned u; } cv; cv.h = h; return cv.u;
}

struct Ptrs { const unsigned short* p[22]; };

__device__ __forceinline__ float loadEl(const unsigned short* p, long i, int f32) {
    return f32 ? ((const float*)p)[i] : bf2f(p[i]);
}

// fp32 scalar region (element offsets in wb)
constexpr int OFF_B1 = 5184;
constexpr int OFF_B2 = 60672;
constexpr int OFF_B3 = 88416;
constexpr int OFF_BO = 89376;

// bf16 tables (ushort offsets in wf)
constexpr int OFFW1A = 0;
constexpr int OFFW1B = 6144;
constexpr int OFFW2 = 12288;
constexpr int OFFW3 = 67584;
constexpr int OFFWO = 95232;
constexpr int OFFBT = 99840;    // bias FP32 [4 cls][64 query][64 key], x log2e (f32 in u16 space)

constexpr int H2SZ = 9437184;   // u16 elems per branch ([2][147456][32])
constexpr float QSCALE = 0.51006973f;   // 8^-0.5 * log2e (pre-folded into br0 weights)

// flag detection: sample 2048 even u16s of x
__device__ __forceinline__ int detect_f32(const unsigned short* x) {
    __shared__ int cnt;
    if (threadIdx.x == 0) cnt = 0;
    __syncthreads();
    int crazy = 0;
    for (int i = threadIdx.x; i < 2048; i += 256) {
        unsigned short u = x[2 * i];
        int e = (u >> 7) & 0xFF;
        if (e >= 0x90) crazy++;
    }
    atomicAdd(&cnt, crazy);
    __syncthreads();
    return (cnt > 32) ? 1 : 0;
}

// ---------- prep (grid 1024; computes dtype flag per block) ----------
__global__ __launch_bounds__(256) void prep_kern(Ptrs in, float* wb, unsigned short* wf,
                                                 unsigned short* xc, int* flagOut) {
    const int f32 = detect_f32(in.p[0]);
    if (blockIdx.x == 0 && threadIdx.x == 0) *flagOut = f32;
    int tid = blockIdx.x * 256 + threadIdx.x;
    int nth = gridDim.x * 256;
    for (int i = tid; i < 192; i += nth) wb[OFF_B1 + i] = loadEl(in.p[2 + 6 * (i / 64)], i % 64, f32);
    for (int i = tid; i < 96;  i += nth) wb[OFF_B2 + i] = loadEl(in.p[4 + 6 * (i / 32)], i % 32, f32);
    // b3: branch 0 (Q) pre-scaled by QSCALE
    for (int i = tid; i < 96;  i += nth)
        wb[OFF_B3 + i] = loadEl(in.p[6 + 6 * (i / 32)], i % 32, f32) * (i < 32 ? QSCALE : 1.f);
    for (int i = tid; i < 3;   i += nth) wb[OFF_BO + i] = loadEl(in.p[20], i, f32);
    // bias FP32, scaled by log2(e); masks baked. Layout [cls][query][key] (swapped QK^T)
    for (int i = tid; i < 16384; i += nth) {
        int cls = i >> 12, rem = i & 4095, qr = rem >> 6, kk = rem & 63;
        int qh = qr >> 3, qw = qr & 7, kh = kk >> 3, kw = kk & 7;
        float v = loadEl(in.p[21], (kh - qh + 7) * 15 + (kw - qw + 7), f32) * 1.4426950408889634f;
        if ((cls & 1) && ((qh >= 4) != (kh >= 4))) v = -1e30f;
        if ((cls & 2) && ((qw >= 4) != (kw >= 4))) v = -1e30f;
        ((float*)(wf + OFFBT))[i] = v;
    }
    // wf1A: taps 0..7; lane l: n = 4*(l&15)+nt, k -> tap=2q+(j>>2), cin=j&3
    for (int i = tid; i < 3 * 2048; i += nth) {
        int br = i / 2048, r = i % 2048;
        int nt = r / 512, rr = r % 512, lane = rr >> 3, j = rr & 7;
        int qq = lane >> 4, n = 4 * (lane & 15) + nt;
        int tap = 2 * qq + (j >> 2), cin = j & 3;
        float v = (cin < 3) ? loadEl(in.p[1 + 6 * br], n * 27 + cin * 9 + tap, f32) : 0.f;
        wf[OFFW1A + i] = f2bf(v);
    }
    // wf1B: tap 8 only
    for (int i = tid; i < 3 * 2048; i += nth) {
        int br = i / 2048, r = i % 2048;
        int nt = r / 512, rr = r % 512, lane = rr >> 3, j = rr & 7;
        int qq = lane >> 4, n = 4 * (lane & 15) + nt;
        float v = (qq == 0 && j < 3) ? loadEl(in.p[1 + 6 * br], n * 27 + j * 9 + 8, f32) : 0.f;
        wf[OFFW1B + i] = f2bf(v);
    }
    // wf2: conv2 (K=576=tap*64+cin, N=32), n = 2*m+nt
    for (int i = tid; i < 3 * 18432; i += nth) {
        int br = i / 18432, r = i % 18432;
        int frag = r / 512, rr = r % 512, lane = rr >> 3, j = rr & 7;
        int s = frag >> 1, nt = frag & 1;
        int k = s * 32 + ((lane >> 4) << 3) + j, n = 2 * (lane & 15) + nt;
        int cin = k & 63, tap = k >> 6;
        wf[OFFW2 + i] = f2bf(loadEl(in.p[3 + 6 * br], n * 576 + cin * 9 + tap, f32));
    }
    // wf3: conv3 (K=288=tap*32+cin, N=32), n = 2*m+nt; branch 0 (Q) pre-scaled
    for (int i = tid; i < 3 * 9216; i += nth) {
        int br = i / 9216, r = i % 9216;
        int frag = r / 512, rr = r % 512, lane = rr >> 3, j = rr & 7;
        int s = frag >> 1, nt = frag & 1;
        int k = s * 32 + ((lane >> 4) << 3) + j, n = 2 * (lane & 15) + nt;
        int cin = k & 31, tap = k >> 5;
        float v = loadEl(in.p[5 + 6 * br], n * 288 + cin * 9 + tap, f32);
        if (br == 0) v *= QSCALE;
        wf[OFFW3 + i] = f2bf(v);
    }
    // wfO
    for (int i = tid; i < 4608; i += nth) {
        int frag = i / 512, rr = i % 512, lane = rr >> 3, j = rr & 7;
        int k = frag * 32 + ((lane >> 4) << 3) + j, n = lane & 15;
        float v = (n < 3) ? loadEl(in.p[19], n * 288 + (k & 31) * 9 + (k >> 5), f32) : 0.f;
        wf[OFFWO + i] = f2bf(v);
    }
    // xc: NHWC pad4, pixel per thread
    for (int i = tid; i < 294912; i += nth) {
        int b = i / 147456, hw = i % 147456;
        float v0 = loadEl(in.p[0], (long)(b * 3 + 0) * 147456 + hw, f32);
        float v1 = loadEl(in.p[0], (long)(b * 3 + 1) * 147456 + hw, f32);
        float v2 = loadEl(in.p[0], (long)(b * 3 + 2) * 147456 + hw, f32);
        uint2 pk;
        pk.x = pk2bf(v0, v1);
        pk.y = pk2bf(v2, 0.f);
        *(uint2*)(&xc[(unsigned)i * 4u]) = pk;
    }
}

// ---------- fused conv1+conv2 (2-row tiles) ----------
__global__ __launch_bounds__(256) void conv12_mfma(
    const unsigned short* __restrict__ xc, const unsigned short* __restrict__ wf,
    const float* __restrict__ wb, unsigned short* __restrict__ h2all) {
    __shared__ __align__(16) unsigned short sX[6][68][4];
    __shared__ __align__(16) unsigned short sH1[264 * 64];
    const int z = blockIdx.z, br = z >> 1, b = z & 1;
    const int h0 = blockIdx.y * 2, w0 = blockIdx.x * 64;
    const int tid = threadIdx.x;
    const bool edge = (h0 == 0) | (h0 == 382) | (w0 == 0) | (w0 == 320);
    const unsigned short* wf1a = wf + OFFW1A + br * 2048;
    const unsigned short* wf1b = wf + OFFW1B + br * 2048;
    const unsigned short* wf2 = wf + OFFW2 + br * 18432;
    for (int idx = tid; idx < 408; idx += 256) {
        int col = idx % 68, row = idx / 68;
        int gh = h0 + row - 2, gw = w0 + col - 2;
        uint2 v = make_uint2(0, 0);
        if ((unsigned)gh < 384u && (unsigned)gw < 384u)
            v = *(const uint2*)(xc + (((unsigned)(b * 147456 + gh * 384 + gw)) << 2));
        *(uint2*)(&sX[row][col][0]) = v;
    }
    __syncthreads();
    const int lane = tid & 63, wave = tid >> 6;
    const int mcol = lane & 15, q = lane >> 4;
    const int tA0 = 2 * q, tA1 = 2 * q + 1;
    const int khA0 = (tA0 * 11) >> 5, kwA0 = tA0 - khA0 * 3;
    const int khA1 = (tA1 * 11) >> 5, kwA1 = tA1 - khA1 * 3;
    {
        float bn[4];
        bf16x8 wA[4], wB[4];
#pragma unroll
        for (int nt = 0; nt < 4; ++nt) {
            bn[nt] = wb[OFF_B1 + br * 64 + 4 * mcol + nt];
            wA[nt] = *(const bf16x8*)(wf1a + nt * 512 + lane * 8);
            wB[nt] = *(const bf16x8*)(wf1b + nt * 512 + lane * 8);
        }
        for (int t = wave; t < 17; t += 4) {
            int p = t * 16 + mcol; int pcl = p < 263 ? p : 263;
            int r1 = (pcl * 993) >> 16, c1 = pcl - r1 * 66;
            uint2 pa = *(const uint2*)&sX[r1 + khA0][c1 + kwA0][0];
            uint2 pb = *(const uint2*)&sX[r1 + khA1][c1 + kwA1][0];
            uint2 pc2 = *(const uint2*)&sX[r1 + 2][c1 + 2][0];
            U8 ua; ua.u = make_uint4(pa.x, pa.y, pb.x, pb.y);
            U8 ub; ub.u = make_uint4(pc2.x, pc2.y, 0u, 0u);
            f32x4 acc[4];
#pragma unroll
            for (int nt = 0; nt < 4; ++nt) {
                acc[nt] = f32x4{bn[nt], bn[nt], bn[nt], bn[nt]};
                acc[nt] = __builtin_amdgcn_mfma_f32_16x16x32_bf16(ua.v, wA[nt], acc[nt], 0, 0, 0);
                acc[nt] = __builtin_amdgcn_mfma_f32_16x16x32_bf16(ub.v, wB[nt], acc[nt], 0, 0, 0);
            }
#pragma unroll
            for (int r = 0; r < 4; ++r) {
                int p2 = t * 16 + q * 4 + r;
                if (p2 < 264) {
                    unsigned lo = pk2bf(fmaxf(acc[0][r], 0.f), fmaxf(acc[1][r], 0.f));
                    unsigned hi = pk2bf(fmaxf(acc[2][r], 0.f), fmaxf(acc[3][r], 0.f));
                    if (edge) {   // block-uniform: only border blocks pay the bounds math
                        int r2 = (p2 * 993) >> 16, c2 = p2 - r2 * 66;
                        bool inb = ((unsigned)(h0 - 1 + r2) < 384u) && ((unsigned)(w0 - 1 + c2) < 384u);
                        if (!inb) { lo = 0u; hi = 0u; }
                    }
                    int seg = (mcol >> 1) ^ (p2 & 7);
                    *(uint2*)(&sH1[p2 * 64 + seg * 8 + ((mcol & 1) << 2)]) = make_uint2(lo, hi);
                }
            }
        }
    }
    __syncthreads();
    f32x4 acc0[2], acc1[2];
    {
        float b0 = wb[OFF_B2 + br * 32 + 2 * mcol], b1 = wb[OFF_B2 + br * 32 + 2 * mcol + 1];
#pragma unroll
        for (int hr = 0; hr < 2; ++hr) {
            acc0[hr] = f32x4{b0, b0, b0, b0};
            acc1[hr] = f32x4{b1, b1, b1, b1};
        }
    }
    for (int kh = 0; kh < 3; ++kh) {
        const unsigned short* wbase = wf2 + kh * 6 * 1024 + lane * 8;
#pragma unroll
        for (int u = 0; u < 6; ++u) {
            const int kw = u >> 1, segl = (u & 1) * 4 + q;
            bf16x8 bf0 = *(const bf16x8*)(wbase + u * 1024);
            bf16x8 bf1 = *(const bf16x8*)(wbase + u * 1024 + 512);
#pragma unroll
            for (int hr = 0; hr < 2; ++hr) {
                int p = (kh + hr) * 66 + wave * 16 + mcol + kw;
                int seg = segl ^ (p & 7);
                bf16x8 a = *(const bf16x8*)(&sH1[p * 64 + seg * 8]);
                acc0[hr] = __builtin_amdgcn_mfma_f32_16x16x32_bf16(a, bf0, acc0[hr], 0, 0, 0);
                acc1[hr] = __builtin_amdgcn_mfma_f32_16x16x32_bf16(a, bf1, acc1[hr], 0, 0, 0);
            }
        }
    }
    unsigned short* h2 = h2all + (size_t)br * H2SZ;
#pragma unroll
    for (int hr = 0; hr < 2; ++hr) {
        unsigned base = (unsigned)(b * 147456 + (h0 + hr) * 384 + w0 + wave * 16 + q * 4) * 32u + 2u * mcol;
#pragma unroll
        for (int r = 0; r < 4; ++r)
            *(unsigned*)(&h2[base + (unsigned)r * 32u]) =
                pk2bf(fmaxf(acc0[hr][r], 0.f), fmaxf(acc1[hr][r], 0.f));
    }
}

// ---------- fused conv3(QKV)+attention v10: single window, 22KB LDS, plain bounds ----------
// The one untested clean config: v7's verified aliasing (21.8 KB) + v8's per-phase
// staging (compiles to 64 VGPR -> 8 waves/SIMD allowed) + NO min-waves cap (caps caused
// the r7/r8 scratch spills). LDS 22016 -> 7 blocks x 4 waves = 28 waves/CU (87%) with
// barriers spanning only one window's 4 waves. Final wave-supply test.
__global__ __launch_bounds__(256) void qkv_attn_mfma(
    const unsigned short* __restrict__ h2all, const unsigned short* __restrict__ wf,
    const float* __restrict__ wb, unsigned short* __restrict__ att) {
    __shared__ __align__(16) unsigned short sHs[5760];     // 11520 B halo (144*40)
    __shared__ __align__(16) unsigned short sQK[5120];     // 10240 B: Q then K (stride 40)
    unsigned short* sQ = sQK;
    unsigned short* sK = sQK + 2560;
    unsigned short* sVT  = sHs;            // [4][9][72] = 2592 u16, alias post-conv
    unsigned short* sOut = sHs + 2592;     // [64][40] = 2560 u16 (byte off 5184, 16B-aligned)
    unsigned short* sPm  = sQK;            // [4][16][72] = 4608 u16, alias after qa/kb preload

    const int win = blockIdx.x, b = blockIdx.y;
    const int wr = win / 48, wc = win % 48;
    const int tid = threadIdx.x;
    const bool wrapR = (wr == 47), wrapC = (wc == 47);
    const int lane = tid & 63, wave = tid >> 6;
    const int mcol = lane & 15, q = lane >> 4;

    // ---- staging offsets (identical for all 3 branches) ----
    unsigned g_off[3]; int l_off[3]; bool g_ok[3], l_ok[3];
#pragma unroll
    for (int k = 0; k < 3; ++k) {
        int idx = tid + (k << 8);
        l_ok[k] = false; g_ok[k] = false; g_off[k] = 0; l_off[k] = 0;
        if (idx < 576) {
            int seg = idx & 3, t = idx >> 2;
            int c = t % 12, r = t / 12;
            if (!((!wrapR && r >= 10) || (!wrapC && c >= 10))) {
                l_ok[k] = true;
                l_off[k] = t * 40 + seg * 8;
                int gh = wrapR ? (r < 6 ? 379 + r : r - 7) : wr * 8 + 3 + r;
                int gw = wrapC ? (c < 6 ? 379 + c : c - 7) : wc * 8 + 3 + c;
                if ((unsigned)gh < 384u && (unsigned)gw < 384u) {
                    g_ok[k] = true;
                    g_off[k] = (((unsigned)(b * 147456 + gh * 384 + gw)) << 5) + seg * 8;
                }
            }
        }
    }
    auto stage = [&](int br) {
#pragma unroll
        for (int k = 0; k < 3; ++k) if (l_ok[k]) {
            uint4 v = make_uint4(0, 0, 0, 0);
            if (g_ok[k]) v = *(const uint4*)(h2all + (size_t)br * H2SZ + g_off[k]);
            *(uint4*)(&sHs[l_off[k]]) = v;
        }
    };

    // ---- stage branch 0 ----
    stage(0);
    __syncthreads();                                         // [1]

    const int tokA = wave * 16 + mcol;
    const int ihA = tokA >> 3, iwA = tokA & 7;
    const int roA = ihA + ((wrapR && ihA >= 4) ? 2 : 0);   // +2 skips seam pad rows
    const int coA = iwA + ((wrapC && iwA >= 4) ? 2 : 0);
    const int aBase = (roA * 12 + coA) * 40 + q * 8;

    f32x4 a0, a1;
    auto conv3 = [&](int br) {
        const unsigned short* wf3 = wf + OFFW3 + br * 9216;
        float b0 = wb[OFF_B3 + br * 32 + 2 * mcol], b1 = wb[OFF_B3 + br * 32 + 2 * mcol + 1];
        a0 = f32x4{b0, b0, b0, b0};
        a1 = f32x4{b1, b1, b1, b1};
#pragma unroll
        for (int tap = 0; tap < 9; ++tap) {
            const int dh = tap / 3, dw = tap % 3;
            bf16x8 a = *(const bf16x8*)(&sHs[aBase + (dh * 12 + dw) * 40]);
            bf16x8 w0v = *(const bf16x8*)(wf3 + tap * 1024 + lane * 8);
            bf16x8 w1v = *(const bf16x8*)(wf3 + tap * 1024 + 512 + lane * 8);
            a0 = __builtin_amdgcn_mfma_f32_16x16x32_bf16(a, w0v, a0, 0, 0, 0);
            a1 = __builtin_amdgcn_mfma_f32_16x16x32_bf16(a, w1v, a1, 0, 0, 0);
        }
    };

    // ---- phase 0: conv3(br0) -> Q (weights pre-scaled) ----
    conv3(0);
#pragma unroll
    for (int r = 0; r < 4; ++r) {
        int tok = wave * 16 + q * 4 + r;
        *(unsigned*)(&sQ[tok * 40 + 2 * mcol]) = pk2bf(a0[r], a1[r]);
    }
    __syncthreads();                                         // [2] br0 halo reads done
    stage(1);
    __syncthreads();                                         // [3]

    // ---- phase 1: conv3(br1) -> K ----
    conv3(1);
#pragma unroll
    for (int r = 0; r < 4; ++r) {
        int tok = wave * 16 + q * 4 + r;
        *(unsigned*)(&sK[tok * 40 + 2 * mcol]) = pk2bf(a0[r], a1[r]);
    }
    __syncthreads();                                         // [4] br1 halo reads done
    stage(2);
    __syncthreads();                                         // [5]

    // ---- phase 2: conv3(br2) -> V kept in regs ----
    conv3(2);

    // preload qa/kb BEFORE sPm aliases sQ/sK
    const int head = wave;
    const bf16x8 zero8 = {0, 0, 0, 0, 0, 0, 0, 0};
    bf16x8 qa[4], kb[4];
#pragma unroll
    for (int t4 = 0; t4 < 4; ++t4) {
        qa[t4] = (q == 0) ? *(const bf16x8*)(&sQ[(t4 * 16 + mcol) * 40 + head * 8]) : zero8;
        kb[t4] = (q == 0) ? *(const bf16x8*)(&sK[(t4 * 16 + mcol) * 40 + head * 8]) : zero8;
    }
    __syncthreads();   // [6] conv reads + qa/kb preload done -> aliases go live

    // write V^T + ones row into sVT (halo alias)
    {
        int hh = mcol >> 2, d0 = 2 * (mcol & 3);
#pragma unroll
        for (int r = 0; r < 4; ++r) {
            int tok = wave * 16 + q * 4 + r;
            unsigned pk = pk2bf(a0[r], a1[r]);
            sVT[(hh * 9 + d0) * 72 + tok]     = (unsigned short)pk;
            sVT[(hh * 9 + d0 + 1) * 72 + tok] = (unsigned short)(pk >> 16);
        }
        sVT[((tid >> 6) * 9 + 8) * 72 + (tid & 63)] = (unsigned short)0x3f80;  // ones row
    }
    __syncthreads();   // [7] sVT ready

    // ---- attention: wave = head; swapped QK^T; f32 bias ----
    const int cls = (wrapR ? 1 : 0) + (wrapC ? 2 : 0);
    const float* bTf = (const float*)(wf + OFFBT) + cls * 4096;   // [query][key] f32
    bf16x8 vb0 = (mcol < 9) ? *(const bf16x8*)(&sVT[(head * 9 + mcol) * 72 + q * 8]) : zero8;
    bf16x8 vb1 = (mcol < 9) ? *(const bf16x8*)(&sVT[(head * 9 + mcol) * 72 + 32 + q * 8]) : zero8;
#pragma unroll
    for (int mt = 0; mt < 4; ++mt) {
        f32x4 s[4];
#pragma unroll
        for (int nt = 0; nt < 4; ++nt) {
            // D[key = nt*16 + q*4+r][qtok = mt*16 + mcol]; bias[query][key] f32
            const float4 bb = *(const float4*)(bTf + (mt * 16 + mcol) * 64 + nt * 16 + q * 4);
            s[nt] = f32x4{bb.x, bb.y, bb.z, bb.w};
            s[nt] = __builtin_amdgcn_mfma_f32_16x16x32_bf16(kb[nt], qa[mt], s[nt], 0, 0, 0);
        }
#pragma unroll
        for (int nt = 0; nt < 4; ++nt) {
            // masked bias -1e30 -> exp2 -> 0
            float p0 = exp2f(s[nt][0]);
            float p1 = exp2f(s[nt][1]);
            float p2 = exp2f(s[nt][2]);
            float p3 = exp2f(s[nt][3]);
            uint2 w;
            w.x = pk2bf(p0, p1);
            w.y = pk2bf(p2, p3);
            // P[qtok = mcol][key = nt*16 + q*4 ..+3], per-head private region
            *(uint2*)(&sPm[head * 1152 + mcol * 72 + nt * 16 + q * 4]) = w;
        }
        bf16x8 ap0 = *(const bf16x8*)(&sPm[head * 1152 + mcol * 72 + q * 8]);
        bf16x8 ap1 = *(const bf16x8*)(&sPm[head * 1152 + mcol * 72 + 32 + q * 8]);
        f32x4 o = {0.f, 0.f, 0.f, 0.f};
        o = __builtin_amdgcn_mfma_f32_16x16x32_bf16(ap0, vb0, o, 0, 0, 0);
        o = __builtin_amdgcn_mfma_f32_16x16x32_bf16(ap1, vb1, o, 0, 0, 0);
#pragma unroll
        for (int r = 0; r < 4; ++r) {
            float sum = __shfl(o[r], (lane & 48) + 8, 64);
            float val = o[r] * __builtin_amdgcn_rcpf(sum);
            if (mcol < 8) {
                int tok = mt * 16 + q * 4 + r;
                sOut[tok * 40 + head * 8 + mcol] = f2bf(val);
            }
        }
    }
    __syncthreads();   // [8] cross-wave: sOut columns come from all 4 heads
    {
        int tok = tid >> 2, seg = tid & 3;
        int ihh = tok >> 3, iww = tok & 7;
        int px = (wr * 8 + ihh) * 384 + wc * 8 + iww;
        uint4 pk = *(const uint4*)(&sOut[tok * 40 + seg * 8]);
        *(uint4*)(att + (((unsigned)(b * 147456 + px)) << 5) + seg * 8) = pk;
    }
}

// ---------- out conv MFMA (shifted space, NHWC32 in) + inverse roll + residual ----------
__global__ __launch_bounds__(256) void outconv_mfma(
    const unsigned short* __restrict__ att, const unsigned short* __restrict__ x_raw,
    const unsigned short* __restrict__ wf, const float* __restrict__ wb,
    void* __restrict__ outp, const int* __restrict__ flagp) {
    __shared__ __align__(16) unsigned short sIn[6][66][40];
    float* sO = reinterpret_cast<float*>(&sIn[0][0][0]);   // [3][4][68] f32, 3264 B alias
    const int f32 = *flagp;
    const int b = blockIdx.z, h0 = blockIdx.y * 4, w0 = blockIdx.x * 64;
    const int tid = threadIdx.x;
    for (int idx = tid; idx < 1584; idx += 256) {
        int seg = idx & 3, t = idx >> 2, col = t % 66, kr = t / 66;
        int gh = h0 + kr - 1, gw = w0 + col - 1;
        uint4 v = make_uint4(0, 0, 0, 0);
        if ((unsigned)gh < 384u && (unsigned)gw < 384u)
            v = *(const uint4*)(att + (((unsigned)(b * 147456 + gh * 384 + gw)) << 5) + seg * 8);
        *(uint4*)(&sIn[kr][col][seg * 8]) = v;
    }
    __syncthreads();
    const int lane = tid & 63, wave = tid >> 6;
    const int mcol = lane & 15, q = lane >> 4;
    float bn = (mcol < 3) ? wb[OFF_BO + mcol] : 0.f;
    f32x4 acc[4];
#pragma unroll
    for (int hr = 0; hr < 4; ++hr) acc[hr] = f32x4{bn, bn, bn, bn};
    for (int kh = 0; kh < 3; ++kh) {
        const unsigned short* wbase = wf + kh * 3 * 512 + lane * 8;
#pragma unroll
        for (int u = 0; u < 3; ++u) {
            bf16x8 bf = *(const bf16x8*)(wbase + u * 512);
#pragma unroll
            for (int hr = 0; hr < 4; ++hr) {
                bf16x8 a = *(const bf16x8*)(&sIn[kh + hr][wave * 16 + mcol + u][q * 8]);
                acc[hr] = __builtin_amdgcn_mfma_f32_16x16x32_bf16(a, bf, acc[hr], 0, 0, 0);
            }
        }
    }
    __syncthreads();   // all waves done reading sIn -> sO may overwrite it
    if (mcol < 3) {
#pragma unroll
        for (int hr = 0; hr < 4; ++hr)
#pragma unroll
            for (int r = 0; r < 4; ++r)
                sO[(mcol * 4 + hr) * 68 + wave * 16 + q * 4 + r] = acc[hr][r];
    }
    __syncthreads();
    if (tid < 192) {
        int ch = tid >> 6, hr = (tid >> 4) & 3, c4 = tid & 15;
        float4 v = *(const float4*)&sO[(ch * 4 + hr) * 68 + c4 * 4];
        int oh = h0 + hr + 4; if (oh >= 384) oh -= 384;
        int gw = w0 + 4 + (c4 << 2);
        int ow = (gw >= 384) ? gw - 384 : gw;    // 4-col groups stay contiguous across the roll
        unsigned idx = (unsigned)(b * 3 + ch) * 147456u + (unsigned)(oh * 384 + ow);
        if (f32) {
            const float4 xv = *(const float4*)((const float*)x_raw + idx);
            float4 o4;
            o4.x = v.x + xv.x; o4.y = v.y + xv.y; o4.z = v.z + xv.z; o4.w = v.w + xv.w;
            *(float4*)((float*)outp + idx) = o4;
        } else {
            const ushort4 xv = *(const ushort4*)(x_raw + idx);
            ushort4 o4;
            o4.x = f2bf(v.x + bf2f(xv.x));
            o4.y = f2bf(v.y + bf2f(xv.y));
            o4.z = f2bf(v.z + bf2f(xv.z));
            o4.w = f2bf(v.w + bf2f(xv.w));
            *(ushort4*)((unsigned short*)outp + idx) = o4;
        }
    }
}

extern "C" void kernel_launch(void* const* d_in, const int* in_sizes, int n_in,
                              void* d_out, int out_size, void* d_ws, size_t ws_size,
                              hipStream_t stream) {
    Ptrs P;
    for (int i = 0; i < 22; ++i) P.p[i] = (const unsigned short*)d_in[i];
    const unsigned short* x_raw = (const unsigned short*)d_in[0];

    char* ws = (char*)d_ws;
    float* wb = (float*)ws;
    int* flag = (int*)(ws + 448 * 1024);
    unsigned short* wf = (unsigned short*)(ws + 512 * 1024);
    unsigned short* xc = (unsigned short*)(ws + 1024 * 1024);
    unsigned short* h2all = (unsigned short*)(ws + 3670016);                       // 3 br x 18.9MB
    unsigned short* att = (unsigned short*)(ws + 3670016 + (size_t)3 * H2SZ * 2);  // att can't alias h2 (halo reads)

    prep_kern<<<dim3(1024), dim3(256), 0, stream>>>(P, wb, wf, xc, flag);
    conv12_mfma<<<dim3(6, 192, 6), dim3(256), 0, stream>>>(xc, wf, wb, h2all);
    qkv_attn_mfma<<<dim3(2304, 2), dim3(256), 0, stream>>>(h2all, wf, wb, att);
    outconv_mfma<<<dim3(6, 96, 2), dim3(256), 0, stream>>>(att, x_raw, wf + OFFWO,
                                                           wb, d_out, flag);
}

// Round 11
// 249.541 us; speedup vs baseline: 1.0703x; 1.0703x over previous
//
#include <hip/hip_runtime.h>
#include <hip/hip_bf16.h>

typedef __attribute__((ext_vector_type(8))) short bf16x8;
typedef __attribute__((ext_vector_type(4))) float f32x4;

union U8 { uint4 u; bf16x8 v; };

// ---------- bf16 helpers ----------
__device__ __forceinline__ float bf2f(unsigned short u) {
    return __uint_as_float(((unsigned)u) << 16);
}
__device__ __forceinline__ unsigned short f2bf(float f) {
    unsigned u = __float_as_uint(f);
    u += 0x7fffu + ((u >> 16) & 1u);
    return (unsigned short)(u >> 16);
}
__device__ __forceinline__ unsigned pk2bf(float a, float b) {
    __hip_bfloat162 h = __float22bfloat162_rn(make_float2(a, b));
    union { __hip_bfloat162 h; unsigned u; } cv; cv.h = h; return cv.u;
}

struct Ptrs { const unsigned short* p[22]; };

__device__ __forceinline__ float loadEl(const unsigned short* p, long i, int f32) {
    return f32 ? ((const float*)p)[i] : bf2f(p[i]);
}

// fp32 scalar region (element offsets in wb)
constexpr int OFF_B1 = 5184;
constexpr int OFF_B2 = 60672;
constexpr int OFF_B3 = 88416;
constexpr int OFF_BO = 89376;

// bf16 tables (ushort offsets in wf)
constexpr int OFFW1A = 0;
constexpr int OFFW1B = 6144;
constexpr int OFFW2 = 12288;
constexpr int OFFW3 = 67584;
constexpr int OFFWO = 95232;
constexpr int OFFBT = 99840;    // biasT bf16 [4 cls][64 query][64 key], x log2e (TRANSPOSED r4)

constexpr int H2SZ = 9437184;   // u16 elems per branch ([2][147456][32])

// flag detection: sample 2048 even u16s of x
__device__ __forceinline__ int detect_f32(const unsigned short* x) {
    __shared__ int cnt;
    if (threadIdx.x == 0) cnt = 0;
    __syncthreads();
    int crazy = 0;
    for (int i = threadIdx.x; i < 2048; i += 256) {
        unsigned short u = x[2 * i];
        int e = (u >> 7) & 0xFF;
        if (e >= 0x90) crazy++;
    }
    atomicAdd(&cnt, crazy);
    __syncthreads();
    return (cnt > 32) ? 1 : 0;
}

// ---------- prep (grid 1024; computes dtype flag per block) ----------
__global__ __launch_bounds__(256) void prep_kern(Ptrs in, float* wb, unsigned short* wf,
                                                 unsigned short* xc, int* flagOut) {
    const int f32 = detect_f32(in.p[0]);
    if (blockIdx.x == 0 && threadIdx.x == 0) *flagOut = f32;
    int tid = blockIdx.x * 256 + threadIdx.x;
    int nth = gridDim.x * 256;
    for (int i = tid; i < 192; i += nth) wb[OFF_B1 + i] = loadEl(in.p[2 + 6 * (i / 64)], i % 64, f32);
    for (int i = tid; i < 96;  i += nth) wb[OFF_B2 + i] = loadEl(in.p[4 + 6 * (i / 32)], i % 32, f32);
    for (int i = tid; i < 96;  i += nth) wb[OFF_B3 + i] = loadEl(in.p[6 + 6 * (i / 32)], i % 32, f32);
    for (int i = tid; i < 3;   i += nth) wb[OFF_BO + i] = loadEl(in.p[20], i, f32);
    // biasT bf16, scaled by log2(e); masks baked. Layout [cls][query][key] (for swapped QK^T)
    for (int i = tid; i < 16384; i += nth) {
        int cls = i >> 12, rem = i & 4095, qr = rem >> 6, kk = rem & 63;
        int qh = qr >> 3, qw = qr & 7, kh = kk >> 3, kw = kk & 7;
        float v = loadEl(in.p[21], (kh - qh + 7) * 15 + (kw - qw + 7), f32) * 1.4426950408889634f;
        if ((cls & 1) && ((qh >= 4) != (kh >= 4))) v = -1e30f;
        if ((cls & 2) && ((qw >= 4) != (kw >= 4))) v = -1e30f;
        wf[OFFBT + i] = f2bf(v);
    }
    // wf1A: taps 0..7; lane l: n = 4*(l&15)+nt, k -> tap=2q+(j>>2), cin=j&3
    for (int i = tid; i < 3 * 2048; i += nth) {
        int br = i / 2048, r = i % 2048;
        int nt = r / 512, rr = r % 512, lane = rr >> 3, j = rr & 7;
        int qq = lane >> 4, n = 4 * (lane & 15) + nt;
        int tap = 2 * qq + (j >> 2), cin = j & 3;
        float v = (cin < 3) ? loadEl(in.p[1 + 6 * br], n * 27 + cin * 9 + tap, f32) : 0.f;
        wf[OFFW1A + i] = f2bf(v);
    }
    // wf1B: tap 8 only
    for (int i = tid; i < 3 * 2048; i += nth) {
        int br = i / 2048, r = i % 2048;
        int nt = r / 512, rr = r % 512, lane = rr >> 3, j = rr & 7;
        int qq = lane >> 4, n = 4 * (lane & 15) + nt;
        float v = (qq == 0 && j < 3) ? loadEl(in.p[1 + 6 * br], n * 27 + j * 9 + 8, f32) : 0.f;
        wf[OFFW1B + i] = f2bf(v);
    }
    // wf2: conv2 (K=576=tap*64+cin, N=32), n = 2*m+nt
    for (int i = tid; i < 3 * 18432; i += nth) {
        int br = i / 18432, r = i % 18432;
        int frag = r / 512, rr = r % 512, lane = rr >> 3, j = rr & 7;
        int s = frag >> 1, nt = frag & 1;
        int k = s * 32 + ((lane >> 4) << 3) + j, n = 2 * (lane & 15) + nt;
        int cin = k & 63, tap = k >> 6;
        wf[OFFW2 + i] = f2bf(loadEl(in.p[3 + 6 * br], n * 576 + cin * 9 + tap, f32));
    }
    // wf3: conv3 (K=288=tap*32+cin, N=32), n = 2*m+nt
    for (int i = tid; i < 3 * 9216; i += nth) {
        int br = i / 9216, r = i % 9216;
        int frag = r / 512, rr = r % 512, lane = rr >> 3, j = rr & 7;
        int s = frag >> 1, nt = frag & 1;
        int k = s * 32 + ((lane >> 4) << 3) + j, n = 2 * (lane & 15) + nt;
        int cin = k & 31, tap = k >> 5;
        wf[OFFW3 + i] = f2bf(loadEl(in.p[5 + 6 * br], n * 288 + cin * 9 + tap, f32));
    }
    // wfO
    for (int i = tid; i < 4608; i += nth) {
        int frag = i / 512, rr = i % 512, lane = rr >> 3, j = rr & 7;
        int k = frag * 32 + ((lane >> 4) << 3) + j, n = lane & 15;
        float v = (n < 3) ? loadEl(in.p[19], n * 288 + (k & 31) * 9 + (k >> 5), f32) : 0.f;
        wf[OFFWO + i] = f2bf(v);
    }
    // xc: NHWC pad4, pixel per thread
    for (int i = tid; i < 294912; i += nth) {
        int b = i / 147456, hw = i % 147456;
        float v0 = loadEl(in.p[0], (long)(b * 3 + 0) * 147456 + hw, f32);
        float v1 = loadEl(in.p[0], (long)(b * 3 + 1) * 147456 + hw, f32);
        float v2 = loadEl(in.p[0], (long)(b * 3 + 2) * 147456 + hw, f32);
        uint2 pk;
        pk.x = pk2bf(v0, v1);
        pk.y = pk2bf(v2, 0.f);
        *(uint2*)(&xc[(unsigned)i * 4u]) = pk;
    }
}

// ---------- fused conv1+conv2, XOR-swizzled sH1 (r10) + 32-bit addr + edge fast path ----------
__global__ __launch_bounds__(256) void conv12_mfma(
    const unsigned short* __restrict__ xc, const unsigned short* __restrict__ wf,
    const float* __restrict__ wb, unsigned short* __restrict__ h2all) {
    __shared__ __align__(16) unsigned short sX[6][68][4];
    __shared__ __align__(16) unsigned short sH1[264 * 64];
    const int z = blockIdx.z, br = z >> 1, b = z & 1;
    const int h0 = blockIdx.y * 2, w0 = blockIdx.x * 64;
    const int tid = threadIdx.x;
    const bool edge = (h0 == 0) | (h0 == 382) | (w0 == 0) | (w0 == 320);
    const unsigned short* wf1a = wf + OFFW1A + br * 2048;
    const unsigned short* wf1b = wf + OFFW1B + br * 2048;
    const unsigned short* wf2 = wf + OFFW2 + br * 18432;
    for (int idx = tid; idx < 408; idx += 256) {
        int col = idx % 68, row = idx / 68;
        int gh = h0 + row - 2, gw = w0 + col - 2;
        uint2 v = make_uint2(0, 0);
        if ((unsigned)gh < 384u && (unsigned)gw < 384u)
            v = *(const uint2*)(xc + (((unsigned)(b * 147456 + gh * 384 + gw)) << 2));
        *(uint2*)(&sX[row][col][0]) = v;
    }
    __syncthreads();
    const int lane = tid & 63, wave = tid >> 6;
    const int mcol = lane & 15, q = lane >> 4;
    const int tA0 = 2 * q, tA1 = 2 * q + 1;
    const int khA0 = (tA0 * 11) >> 5, kwA0 = tA0 - khA0 * 3;
    const int khA1 = (tA1 * 11) >> 5, kwA1 = tA1 - khA1 * 3;
    {
        float bn[4];
        bf16x8 wA[4], wB[4];
#pragma unroll
        for (int nt = 0; nt < 4; ++nt) {
            bn[nt] = wb[OFF_B1 + br * 64 + 4 * mcol + nt];
            wA[nt] = *(const bf16x8*)(wf1a + nt * 512 + lane * 8);
            wB[nt] = *(const bf16x8*)(wf1b + nt * 512 + lane * 8);
        }
        for (int t = wave; t < 17; t += 4) {
            int p = t * 16 + mcol; int pcl = p < 263 ? p : 263;
            int r1 = (pcl * 993) >> 16, c1 = pcl - r1 * 66;
            uint2 pa = *(const uint2*)&sX[r1 + khA0][c1 + kwA0][0];
            uint2 pb = *(const uint2*)&sX[r1 + khA1][c1 + kwA1][0];
            uint2 pc2 = *(const uint2*)&sX[r1 + 2][c1 + 2][0];
            U8 ua; ua.u = make_uint4(pa.x, pa.y, pb.x, pb.y);
            U8 ub; ub.u = make_uint4(pc2.x, pc2.y, 0u, 0u);
            f32x4 acc[4];
#pragma unroll
            for (int nt = 0; nt < 4; ++nt) {
                acc[nt] = f32x4{bn[nt], bn[nt], bn[nt], bn[nt]};
                acc[nt] = __builtin_amdgcn_mfma_f32_16x16x32_bf16(ua.v, wA[nt], acc[nt], 0, 0, 0);
                acc[nt] = __builtin_amdgcn_mfma_f32_16x16x32_bf16(ub.v, wB[nt], acc[nt], 0, 0, 0);
            }
#pragma unroll
            for (int r = 0; r < 4; ++r) {
                int p2 = t * 16 + q * 4 + r;
                if (p2 < 264) {
                    unsigned lo = pk2bf(fmaxf(acc[0][r], 0.f), fmaxf(acc[1][r], 0.f));
                    unsigned hi = pk2bf(fmaxf(acc[2][r], 0.f), fmaxf(acc[3][r], 0.f));
                    if (edge) {   // block-uniform: only border blocks pay the bounds math
                        int r2 = (p2 * 993) >> 16, c2 = p2 - r2 * 66;
                        bool inb = ((unsigned)(h0 - 1 + r2) < 384u) && ((unsigned)(w0 - 1 + c2) < 384u);
                        if (!inb) { lo = 0u; hi = 0u; }
                    }
                    int seg = (mcol >> 1) ^ (p2 & 7);
                    *(uint2*)(&sH1[p2 * 64 + seg * 8 + ((mcol & 1) << 2)]) = make_uint2(lo, hi);
                }
            }
        }
    }
    __syncthreads();
    f32x4 acc0[2], acc1[2];
    {
        float b0 = wb[OFF_B2 + br * 32 + 2 * mcol], b1 = wb[OFF_B2 + br * 32 + 2 * mcol + 1];
#pragma unroll
        for (int hr = 0; hr < 2; ++hr) {
            acc0[hr] = f32x4{b0, b0, b0, b0};
            acc1[hr] = f32x4{b1, b1, b1, b1};
        }
    }
    for (int kh = 0; kh < 3; ++kh) {
        const unsigned short* wbase = wf2 + kh * 6 * 1024 + lane * 8;
#pragma unroll
        for (int u = 0; u < 6; ++u) {
            const int kw = u >> 1, segl = (u & 1) * 4 + q;
            bf16x8 bf0 = *(const bf16x8*)(wbase + u * 1024);
            bf16x8 bf1 = *(const bf16x8*)(wbase + u * 1024 + 512);
#pragma unroll
            for (int hr = 0; hr < 2; ++hr) {
                int p = (kh + hr) * 66 + wave * 16 + mcol + kw;
                int seg = segl ^ (p & 7);
                bf16x8 a = *(const bf16x8*)(&sH1[p * 64 + seg * 8]);
                acc0[hr] = __builtin_amdgcn_mfma_f32_16x16x32_bf16(a, bf0, acc0[hr], 0, 0, 0);
                acc1[hr] = __builtin_amdgcn_mfma_f32_16x16x32_bf16(a, bf1, acc1[hr], 0, 0, 0);
            }
        }
    }
    unsigned short* h2 = h2all + (size_t)br * H2SZ;
#pragma unroll
    for (int hr = 0; hr < 2; ++hr) {
        unsigned base = (unsigned)(b * 147456 + (h0 + hr) * 384 + w0 + wave * 16 + q * 4) * 32u + 2u * mcol;
#pragma unroll
        for (int r = 0; r < 4; ++r)
            *(unsigned*)(&h2[base + (unsigned)r * 32u]) =
                pk2bf(fmaxf(acc0[hr][r], 0.f), fmaxf(acc1[hr][r], 0.f));
    }
}

// ---------- fused conv3(QKV)+attention v4 (the best-measured variant: r4, 251.66us) ----------
// Upfront halo loads into R[3][3]; swapped QK^T (s = mfma(K,Q)) so P writes are
// ds_write_b64 and the PV A-read is conflict-free stride-72 b128; bias [q][k] in prep.
__global__ __launch_bounds__(256, 6) void qkv_attn_mfma(
    const unsigned short* __restrict__ h2all, const unsigned short* __restrict__ wf,
    const float* __restrict__ wb, unsigned short* __restrict__ att) {
    __shared__ __align__(16) unsigned short sHs[144 * 40];      // 11520 B: 1-branch 12x12 halo
    __shared__ __align__(16) unsigned short sQ[64 * 40];        // 5120 B (pre-scaled Q)
    __shared__ __align__(16) unsigned short sK[64 * 40];        // 5120 B
    __shared__ __align__(16) unsigned short sVT[4][9][72];      // 5184 B (V^T + ones row)
    unsigned short* sPm = sHs;   // [head*1152 + qrow*72 + key], alias after conv phase
    unsigned short* sOut = sK;   // [tok*40 + ch], alias after kb consumed

    const int win = blockIdx.x, b = blockIdx.y;
    const int wr = win / 48, wc = win % 48;
    const int tid = threadIdx.x;
    const bool wrapR = (wr == 47), wrapC = (wc == 47);
    const int lane = tid & 63, wave = tid >> 6;
    const int mcol = lane & 15, q = lane >> 4;

    // ---- precompute staging offsets once (identical for all 3 branches) ----
    unsigned g_off[3]; int l_off[3]; bool g_ok[3], l_ok[3];
#pragma unroll
    for (int k = 0; k < 3; ++k) {
        int idx = tid + (k << 8);
        l_ok[k] = false; g_ok[k] = false; g_off[k] = 0; l_off[k] = 0;
        if (idx < 576) {
            int seg = idx & 3, t = idx >> 2;
            int c = t % 12, r = t / 12;
            if (!((!wrapR && r >= 10) || (!wrapC && c >= 10))) {
                l_ok[k] = true;
                l_off[k] = t * 40 + seg * 8;
                int gh = wrapR ? (r < 6 ? 379 + r : r - 7) : wr * 8 + 3 + r;
                int gw = wrapC ? (c < 6 ? 379 + c : c - 7) : wc * 8 + 3 + c;
                if ((unsigned)gh < 384u && (unsigned)gw < 384u) {
                    g_ok[k] = true;
                    g_off[k] = (((unsigned)(b * 147456 + gh * 384 + gw)) << 5) + seg * 8;
                }
            }
        }
    }

    // ---- issue ALL branch halo loads up front (br0 first: its vmcnt drains first) ----
    uint4 R[3][3];
#pragma unroll
    for (int br = 0; br < 3; ++br)
#pragma unroll
        for (int k = 0; k < 3; ++k) {
            R[br][k] = make_uint4(0, 0, 0, 0);
            if (g_ok[k]) R[br][k] = *(const uint4*)(h2all + (size_t)br * H2SZ + g_off[k]);
        }

    // ones row (rowsum column of V^T)
    {
        int hh = tid >> 6, tok = tid & 63;
        sVT[hh][8][tok] = (unsigned short)0x3f80;
    }

    // ---- stage branch 0 ----
#pragma unroll
    for (int k = 0; k < 3; ++k) if (l_ok[k]) *(uint4*)(&sHs[l_off[k]]) = R[0][k];
    __syncthreads();

    const int tokA = wave * 16 + mcol;
    const int ihA = tokA >> 3, iwA = tokA & 7;
    const int roA = ihA + ((wrapR && ihA >= 4) ? 2 : 0);   // +2 skips seam pad rows
    const int coA = iwA + ((wrapC && iwA >= 4) ? 2 : 0);
    const int aBase = (roA * 12 + coA) * 40 + q * 8;

    f32x4 a0, a1;
    auto conv3 = [&](int br) {
        const unsigned short* wf3 = wf + OFFW3 + br * 9216;
        float b0 = wb[OFF_B3 + br * 32 + 2 * mcol], b1 = wb[OFF_B3 + br * 32 + 2 * mcol + 1];
        a0 = f32x4{b0, b0, b0, b0};
        a1 = f32x4{b1, b1, b1, b1};
#pragma unroll
        for (int tap = 0; tap < 9; ++tap) {
            const int dh = tap / 3, dw = tap % 3;
            bf16x8 a = *(const bf16x8*)(&sHs[aBase + (dh * 12 + dw) * 40]);
            bf16x8 w0v = *(const bf16x8*)(wf3 + tap * 1024 + lane * 8);
            bf16x8 w1v = *(const bf16x8*)(wf3 + tap * 1024 + 512 + lane * 8);
            a0 = __builtin_amdgcn_mfma_f32_16x16x32_bf16(a, w0v, a0, 0, 0, 0);
            a1 = __builtin_amdgcn_mfma_f32_16x16x32_bf16(a, w1v, a1, 0, 0, 0);
        }
    };

    // ---- branch 0 -> Q ----
    conv3(0);
    {
        const float scale = 0.51006973f;   // 8^-0.5 * log2e folded into Q
#pragma unroll
        for (int r = 0; r < 4; ++r) {
            int tok = wave * 16 + q * 4 + r;
            *(unsigned*)(&sQ[tok * 40 + 2 * mcol]) = pk2bf(a0[r] * scale, a1[r] * scale);
        }
    }
    __syncthreads();
#pragma unroll
    for (int k = 0; k < 3; ++k) if (l_ok[k]) *(uint4*)(&sHs[l_off[k]]) = R[1][k];
    __syncthreads();
    // ---- branch 1 -> K ----
    conv3(1);
#pragma unroll
    for (int r = 0; r < 4; ++r) {
        int tok = wave * 16 + q * 4 + r;
        *(unsigned*)(&sK[tok * 40 + 2 * mcol]) = pk2bf(a0[r], a1[r]);
    }
    __syncthreads();
#pragma unroll
    for (int k = 0; k < 3; ++k) if (l_ok[k]) *(uint4*)(&sHs[l_off[k]]) = R[2][k];
    __syncthreads();
    // ---- branch 2 -> V (scatter into transposed layout, pair-packed cvt) ----
    conv3(2);
    {
        int hh = mcol >> 2, d0 = 2 * (mcol & 3);
#pragma unroll
        for (int r = 0; r < 4; ++r) {
            int tok = wave * 16 + q * 4 + r;
            unsigned pk = pk2bf(a0[r], a1[r]);
            sVT[hh][d0][tok]     = (unsigned short)pk;
            sVT[hh][d0 + 1][tok] = (unsigned short)(pk >> 16);
        }
    }
    __syncthreads();   // conv phase done: sHs dead (-> sPm), sQ/sK/sVT ready

    // ---- attention: wave = head; swapped QK^T ----
    const int head = wave;
    const int cls = (wrapR ? 1 : 0) + (wrapC ? 2 : 0);
    const unsigned short* bT = wf + OFFBT + cls * 4096;   // [query][key]
    const bf16x8 zero8 = {0, 0, 0, 0, 0, 0, 0, 0};
    bf16x8 kb[4];
#pragma unroll
    for (int nt = 0; nt < 4; ++nt)
        kb[nt] = (q == 0) ? *(const bf16x8*)(&sK[(nt * 16 + mcol) * 40 + head * 8]) : zero8;
    bf16x8 vb0 = (mcol < 9) ? *(const bf16x8*)(&sVT[head][mcol][q * 8]) : zero8;
    bf16x8 vb1 = (mcol < 9) ? *(const bf16x8*)(&sVT[head][mcol][32 + q * 8]) : zero8;
    __syncthreads();   // kb consumed by all waves -> sOut may overwrite sK
#pragma unroll
    for (int mt = 0; mt < 4; ++mt) {
        bf16x8 qa = (q == 0) ? *(const bf16x8*)(&sQ[(mt * 16 + mcol) * 40 + head * 8]) : zero8;
        f32x4 s[4];
#pragma unroll
        for (int nt = 0; nt < 4; ++nt) {
            // D[key = nt*16 + q*4+r][qtok = mt*16 + mcol]; bias[query][key]
            const ushort4 bb = *(const ushort4*)(bT + (mt * 16 + mcol) * 64 + nt * 16 + q * 4);
            s[nt] = f32x4{bf2f(bb.x), bf2f(bb.y), bf2f(bb.z), bf2f(bb.w)};
            s[nt] = __builtin_amdgcn_mfma_f32_16x16x32_bf16(kb[nt], qa, s[nt], 0, 0, 0);
        }
#pragma unroll
        for (int nt = 0; nt < 4; ++nt) {
            // masked bias -1e30 -> exp2 -> 0 (no clamp needed; scores are small)
            float p0 = exp2f(s[nt][0]);
            float p1 = exp2f(s[nt][1]);
            float p2 = exp2f(s[nt][2]);
            float p3 = exp2f(s[nt][3]);
            uint2 w;
            w.x = pk2bf(p0, p1);
            w.y = pk2bf(p2, p3);
            // P[qtok = mcol (within mt)][key = nt*16 + q*4 .. +3] row-major, stride 72
            *(uint2*)(&sPm[head * 1152 + mcol * 72 + nt * 16 + q * 4]) = w;
        }
        bf16x8 ap0 = *(const bf16x8*)(&sPm[head * 1152 + mcol * 72 + q * 8]);
        bf16x8 ap1 = *(const bf16x8*)(&sPm[head * 1152 + mcol * 72 + 32 + q * 8]);
        f32x4 o = {0.f, 0.f, 0.f, 0.f};
        o = __builtin_amdgcn_mfma_f32_16x16x32_bf16(ap0, vb0, o, 0, 0, 0);
        o = __builtin_amdgcn_mfma_f32_16x16x32_bf16(ap1, vb1, o, 0, 0, 0);
#pragma unroll
        for (int r = 0; r < 4; ++r) {
            float sum = __shfl(o[r], (lane & 48) + 8, 64);
            float val = o[r] * __builtin_amdgcn_rcpf(sum);
            if (mcol < 8) {
                int tok = mt * 16 + q * 4 + r;
                sOut[tok * 40 + head * 8 + mcol] = f2bf(val);
            }
        }
    }
    __syncthreads();   // cross-wave: sOut columns come from all 4 heads
    {
        int tok = tid >> 2, seg = tid & 3;
        int ihh = tok >> 3, iww = tok & 7;
        int px = (wr * 8 + ihh) * 384 + wc * 8 + iww;
        uint4 pk = *(const uint4*)(&sOut[tok * 40 + seg * 8]);
        *(uint4*)(att + (((unsigned)(b * 147456 + px)) << 5) + seg * 8) = pk;
    }
}

// ---------- out conv MFMA (shifted space, NHWC32 in) + inverse roll + residual ----------
// results staged in LDS (aliased on dead sIn) then coalesced vectorized epilogue
__global__ __launch_bounds__(256) void outconv_mfma(
    const unsigned short* __restrict__ att, const unsigned short* __restrict__ x_raw,
    const unsigned short* __restrict__ wf, const float* __restrict__ wb,
    void* __restrict__ outp, const int* __restrict__ flagp) {
    __shared__ __align__(16) unsigned short sIn[6][66][40];
    float* sO = reinterpret_cast<float*>(&sIn[0][0][0]);   // [3][4][68] f32, 3264 B alias
    const int f32 = *flagp;
    const int b = blockIdx.z, h0 = blockIdx.y * 4, w0 = blockIdx.x * 64;
    const int tid = threadIdx.x;
    for (int idx = tid; idx < 1584; idx += 256) {
        int seg = idx & 3, t = idx >> 2, col = t % 66, kr = t / 66;
        int gh = h0 + kr - 1, gw = w0 + col - 1;
        uint4 v = make_uint4(0, 0, 0, 0);
        if ((unsigned)gh < 384u && (unsigned)gw < 384u)
            v = *(const uint4*)(att + (((unsigned)(b * 147456 + gh * 384 + gw)) << 5) + seg * 8);
        *(uint4*)(&sIn[kr][col][seg * 8]) = v;
    }
    __syncthreads();
    const int lane = tid & 63, wave = tid >> 6;
    const int mcol = lane & 15, q = lane >> 4;
    float bn = (mcol < 3) ? wb[OFF_BO + mcol] : 0.f;
    f32x4 acc[4];
#pragma unroll
    for (int hr = 0; hr < 4; ++hr) acc[hr] = f32x4{bn, bn, bn, bn};
    for (int kh = 0; kh < 3; ++kh) {
        const unsigned short* wbase = wf + kh * 3 * 512 + lane * 8;
#pragma unroll
        for (int u = 0; u < 3; ++u) {
            bf16x8 bf = *(const bf16x8*)(wbase + u * 512);
#pragma unroll
            for (int hr = 0; hr < 4; ++hr) {
                bf16x8 a = *(const bf16x8*)(&sIn[kh + hr][wave * 16 + mcol + u][q * 8]);
                acc[hr] = __builtin_amdgcn_mfma_f32_16x16x32_bf16(a, bf, acc[hr], 0, 0, 0);
            }
        }
    }
    __syncthreads();   // all waves done reading sIn -> sO may overwrite it
    if (mcol < 3) {
#pragma unroll
        for (int hr = 0; hr < 4; ++hr)
#pragma unroll
            for (int r = 0; r < 4; ++r)
                sO[(mcol * 4 + hr) * 68 + wave * 16 + q * 4 + r] = acc[hr][r];
    }
    __syncthreads();
    if (tid < 192) {
        int ch = tid >> 6, hr = (tid >> 4) & 3, c4 = tid & 15;
        float4 v = *(const float4*)&sO[(ch * 4 + hr) * 68 + c4 * 4];
        int oh = h0 + hr + 4; if (oh >= 384) oh -= 384;
        int gw = w0 + 4 + (c4 << 2);
        int ow = (gw >= 384) ? gw - 384 : gw;    // 4-col groups stay contiguous across the roll
        unsigned idx = (unsigned)(b * 3 + ch) * 147456u + (unsigned)(oh * 384 + ow);
        if (f32) {
            const float4 xv = *(const float4*)((const float*)x_raw + idx);
            float4 o4;
            o4.x = v.x + xv.x; o4.y = v.y + xv.y; o4.z = v.z + xv.z; o4.w = v.w + xv.w;
            *(float4*)((float*)outp + idx) = o4;
        } else {
            const ushort4 xv = *(const ushort4*)(x_raw + idx);
            ushort4 o4;
            o4.x = f2bf(v.x + bf2f(xv.x));
            o4.y = f2bf(v.y + bf2f(xv.y));
            o4.z = f2bf(v.z + bf2f(xv.z));
            o4.w = f2bf(v.w + bf2f(xv.w));
            *(ushort4*)((unsigned short*)outp + idx) = o4;
        }
    }
}

extern "C" void kernel_launch(void* const* d_in, const int* in_sizes, int n_in,
                              void* d_out, int out_size, void* d_ws, size_t ws_size,
                              hipStream_t stream) {
    Ptrs P;
    for (int i = 0; i < 22; ++i) P.p[i] = (const unsigned short*)d_in[i];
    const unsigned short* x_raw = (const unsigned short*)d_in[0];

    char* ws = (char*)d_ws;
    float* wb = (float*)ws;
    int* flag = (int*)(ws + 448 * 1024);
    unsigned short* wf = (unsigned short*)(ws + 512 * 1024);
    unsigned short* xc = (unsigned short*)(ws + 1024 * 1024);
    unsigned short* h2all = (unsigned short*)(ws + 3670016);                       // 3 br x 18.9MB
    unsigned short* att = (unsigned short*)(ws + 3670016 + (size_t)3 * H2SZ * 2);  // att can't alias h2 (halo reads)

    prep_kern<<<dim3(1024), dim3(256), 0, stream>>>(P, wb, wf, xc, flag);
    conv12_mfma<<<dim3(6, 192, 6), dim3(256), 0, stream>>>(xc, wf, wb, h2all);
    qkv_attn_mfma<<<dim3(2304, 2), dim3(256), 0, stream>>>(h2all, wf, wb, att);
    outconv_mfma<<<dim3(6, 96, 2), dim3(256), 0, stream>>>(att, x_raw, wf + OFFWO,
                                                           wb, d_out, flag);
}